// Round 11
// baseline (697.021 us; speedup 1.0000x reference)
//
#include <hip/hip_runtime.h>
#include <hip/hip_bf16.h>
#include <math.h>

typedef __attribute__((ext_vector_type(8))) short short8;
typedef __attribute__((ext_vector_type(4))) float floatx4;
using bf16_t = __hip_bfloat16;

#define GLOAD16(gp, lp)                                                        \
  __builtin_amdgcn_global_load_lds(                                            \
      (const __attribute__((address_space(1))) unsigned int*)(gp),             \
      (__attribute__((address_space(3))) unsigned int*)(lp), 16, 0, 0)

#define CFENCE() asm volatile("" ::: "memory")
#define BAR()                                                                  \
  do {                                                                         \
    CFENCE();                                                                  \
    __builtin_amdgcn_s_barrier();                                              \
    CFENCE();                                                                  \
  } while (0)

// ---------------------------------------------------------------- converts --
// y selects one of 3 matrices (adj, W0, W1); plain f32->bf16, no transpose.
__global__ void convert3_f32_to_bf16(const float* __restrict__ s0,
                                     const float* __restrict__ s1,
                                     const float* __restrict__ s2,
                                     bf16_t* __restrict__ d0,
                                     bf16_t* __restrict__ d1,
                                     bf16_t* __restrict__ d2) {
  const float* in = blockIdx.y == 0 ? s0 : (blockIdx.y == 1 ? s1 : s2);
  bf16_t* out = blockIdx.y == 0 ? d0 : (blockIdx.y == 1 ? d1 : d2);
  int i = blockIdx.x * 256 + threadIdx.x;  // 4 elements per thread
  float4 v = ((const float4*)in)[i];
  union { ushort4 u; bf16_t b[4]; } pk;
  pk.b[0] = __float2bfloat16(v.x);
  pk.b[1] = __float2bfloat16(v.y);
  pk.b[2] = __float2bfloat16(v.z);
  pk.b[3] = __float2bfloat16(v.w);
  ((ushort4*)out)[i] = pk.u;
}

// out[c][r] = bf16(in[r][c]); z selects X or ln_w.
__global__ void transpose2_f32_bf16(const float* __restrict__ s0,
                                    const float* __restrict__ s1,
                                    bf16_t* __restrict__ d0,
                                    bf16_t* __restrict__ d1) {
  const float* in = blockIdx.z == 0 ? s0 : s1;
  bf16_t* out = blockIdx.z == 0 ? d0 : d1;
  __shared__ float t[64][65];
  const int r0 = blockIdx.y * 64, c0 = blockIdx.x * 64;
  const int tid = threadIdx.x;
  const int c4 = tid & 15, rr = tid >> 4;
#pragma unroll
  for (int i = 0; i < 4; ++i) {
    const int r = rr + i * 16;
    float4 v = *(const float4*)(in + (size_t)(r0 + r) * 4096 + c0 + c4 * 4);
    t[c4 * 4 + 0][r] = v.x;
    t[c4 * 4 + 1][r] = v.y;
    t[c4 * 4 + 2][r] = v.z;
    t[c4 * 4 + 3][r] = v.w;
  }
  __syncthreads();
  const int r4 = tid & 15, cc = tid >> 4;
#pragma unroll
  for (int i = 0; i < 4; ++i) {
    const int c = cc + i * 16;
    union { ushort4 u; bf16_t b[4]; } pk;
#pragma unroll
    for (int j = 0; j < 4; ++j) pk.b[j] = __float2bfloat16(t[c][r4 * 4 + j]);
    *(ushort4*)(out + (size_t)(c0 + c) * 4096 + r0 + r4 * 4) = pk.u;
  }
}

// ---------------------------------------------------------------- NT GEMM ---
// C[m][n] = sum_k A[m][k]*B[n][k]; bf16 K-fastest operands.
// 256x256 tile, 8 waves (2Mx4N, wave tile 128x64), 16x16x32 MFMA.
// LDS ring-4 of K=32 planes/operand (128 KiB); register-prefetched fragment
// double buffer; per region: {12 ds_read (r+1 frags); 4 gload_lds (plane
// r+3); setprio(1); 32 MFMA (current frags, no waits); setprio(0);
// vmcnt(4); s_barrier}. Pair-XOR swizzle. XCD swizzle.
// EPI 3: fused M5+pool: per-(by,col) partial sum/max of
//        satt[r]*relu(acc+lnb[c])*mask[r]  (no dense output)
// EPI 4: C=bf16(relu(acc)*mask[m]) AND AUX = C^T (LDS-staged transpose)
// EPI 5: C=bf16(X0+relu(acc)*mask[m]) AND AUX=pAtt col-panel partials of
//        x @ att_w (att GEMV fused; lnb param carries att_w)
// EPI 6: merged weight-prep: grid 512 (16Mx32N over stacked B=[W0b;W1b]);
//        writes M0/M1 as two separate 4096-stride matrices (idx split).

#define REGION(R, SRD, SWR, FAN, FBN, FAC, FBC)                                \
  {                                                                            \
    _Pragma("unroll") for (int n = 0; n < 4; ++n)                              \
        FBN[n] = *(const short8*)(smem + 32768 + (SRD) * 8192 + offB_e +       \
                                  n * 512);                                    \
    _Pragma("unroll") for (int m = 0; m < 8; ++m)                              \
        FAN[m] = *(const short8*)(smem + (SRD) * 8192 + offA_e + m * 512);     \
    const size_t koW = (size_t)((((R) + 3) & 127) * 32);                       \
    bf16_t* dA = smem + (SWR) * 8192 + wave * 512;                             \
    bf16_t* dB = smem + 32768 + (SWR) * 8192 + wave * 512;                     \
    GLOAD16(A + gAc0 + koW, dA);                                               \
    GLOAD16(A + gAc1 + koW, dA + 4096);                                        \
    GLOAD16(B + gBc0 + koW, dB);                                               \
    GLOAD16(B + gBc1 + koW, dB + 4096);                                        \
    __builtin_amdgcn_s_setprio(1);                                             \
    _Pragma("unroll") for (int m = 0; m < 8; ++m)                              \
        _Pragma("unroll") for (int n = 0; n < 4; ++n)                          \
            acc[m][n] = __builtin_amdgcn_mfma_f32_16x16x32_bf16(               \
                FAC[m], FBC[n], acc[m][n], 0, 0, 0);                           \
    __builtin_amdgcn_s_setprio(0);                                             \
    asm volatile("s_waitcnt vmcnt(4)" ::: "memory");                           \
    BAR();                                                                     \
  }

template <int EPI>
__global__ __launch_bounds__(512, 2) void gemm_nt(
    const bf16_t* __restrict__ A, const bf16_t* __restrict__ B,
    void* __restrict__ C, void* __restrict__ AUX,
    const bf16_t* __restrict__ X0, const float* __restrict__ rowm,
    const float* __restrict__ satt, const float* __restrict__ lnb) {
  extern __shared__ bf16_t smem[];  // 8 planes x 8192 elems = 128 KiB
  const int tid = threadIdx.x;
  const int wave = tid >> 6, lane = tid & 63;
  const int bid = blockIdx.x;
  int by, bx;
  if constexpr (EPI == 6) {
    const int swz = ((bid & 7) << 6) | (bid >> 3);  // 512 wg bijective
    by = swz >> 5;
    bx = swz & 31;
  } else {
    const int swz = ((bid & 7) << 5) | (bid >> 3);  // 256 wg bijective
    by = swz >> 4;
    bx = swz & 15;
  }
  const int m0 = by * 256, n0 = bx * 256;
  const int wr = wave >> 2, wc = wave & 3;  // 2M x 4N wave grid

  floatx4 acc[8][4] = {};

  // ---- staging source addressing (pre-swizzled global; linear LDS dest).
  const int pr = tid >> 3, ph = tid & 7;
  const int sl8 = ph ^ (pr & 7);                 // logical slot8
  const int rl = (pr << 1) + (sl8 >> 2);         // local row in 128-row call
  const int colg = (sl8 & 3) << 3;               // k element offset (0..24)
  const size_t gAc0 = (size_t)(m0 + rl) * 4096 + colg;
  const size_t gAc1 = gAc0 + (size_t)128 * 4096;
  const size_t gBc0 = (size_t)(n0 + rl) * 4096 + colg;
  const size_t gBc1 = gBc0 + (size_t)128 * 4096;

  // ---- ds_read addressing (16x16x32 frags):
  const int l15 = lane & 15;
  const int phRd = (((lane & 1) << 2) + (lane >> 4)) ^ (l15 >> 1);
  const int offA_e = (wr * 64 + (l15 >> 1)) * 64 + phRd * 8;  // + m*512
  const int offB_e = (wc * 32 + (l15 >> 1)) * 64 + phRd * 8;  // + n*512

  // ---- prologue: stage planes 0,1,2 into slots 0,1,2 (12 loads)
#pragma unroll
  for (int p = 0; p < 3; ++p) {
    bf16_t* dA = smem + p * 8192 + wave * 512;
    bf16_t* dB = smem + 32768 + p * 8192 + wave * 512;
    const size_t ko = (size_t)p * 32;
    GLOAD16(A + gAc0 + ko, dA);
    GLOAD16(A + gAc1 + ko, dA + 4096);
    GLOAD16(B + gBc0 + ko, dB);
    GLOAD16(B + gBc1 + ko, dB + 4096);
  }
  asm volatile("s_waitcnt vmcnt(4)" ::: "memory");  // planes 0,1 landed
  BAR();

  // initial fragment read: region 0 from slot 0
  short8 fA0[8], fB0[4], fA1[8], fB1[4];
#pragma unroll
  for (int n = 0; n < 4; ++n)
    fB0[n] = *(const short8*)(smem + 32768 + offB_e + n * 512);
#pragma unroll
  for (int m = 0; m < 8; ++m)
    fA0[m] = *(const short8*)(smem + offA_e + m * 512);

  for (int r = 0; r < 128; r += 4) {
    REGION(r, 1, 3, fA1, fB1, fA0, fB0)
    REGION(r + 1, 2, 0, fA0, fB0, fA1, fB1)
    REGION(r + 2, 3, 1, fA1, fB1, fA0, fB0)
    REGION(r + 3, 0, 2, fA0, fB0, fA1, fB1)
  }
  asm volatile("s_waitcnt vmcnt(0)" ::: "memory");
  BAR();  // LDS now safe to reuse

  // epilogue: D lane mapping col = lane&15, row = (lane>>4)*4 + u
  const int wmr = wr * 128, wnc = wc * 64;
  const int rr = (lane >> 4) * 4, cc = lane & 15;
  bf16_t* Cb = (bf16_t*)C;

  if constexpr (EPI == 3) {
    // fused: v = satt[r]*relu(acc+lnb[c])*mask[r]; column partial sum & max
    float lb[4];
#pragma unroll
    for (int n = 0; n < 4; ++n) lb[n] = lnb[n0 + wnc + n * 16 + cc];
    float s[4] = {0.f, 0.f, 0.f, 0.f}, mx[4] = {0.f, 0.f, 0.f, 0.f};
#pragma unroll
    for (int m = 0; m < 8; ++m) {
#pragma unroll
      for (int u = 0; u < 4; ++u) {
        const int gr = m0 + wmr + m * 16 + rr + u;
        const float f = satt[gr] * rowm[gr];
#pragma unroll
        for (int n = 0; n < 4; ++n) {
          const float v = fmaxf(acc[m][n][u] + lb[n], 0.f) * f;
          s[n] += v;
          mx[n] = fmaxf(mx[n], v);
        }
      }
    }
#pragma unroll
    for (int n = 0; n < 4; ++n) {
      s[n] += __shfl_xor(s[n], 16);
      s[n] += __shfl_xor(s[n], 32);
      mx[n] = fmaxf(mx[n], __shfl_xor(mx[n], 16));
      mx[n] = fmaxf(mx[n], __shfl_xor(mx[n], 32));
    }
    float* sred = (float*)smem;  // [2][256]
    float* mred = sred + 512;    // [2][256]
    if ((lane >> 4) == 0) {
#pragma unroll
      for (int n = 0; n < 4; ++n) {
        sred[wr * 256 + wnc + n * 16 + cc] = s[n];
        mred[wr * 256 + wnc + n * 16 + cc] = mx[n];
      }
    }
    __syncthreads();
    if (tid < 256) {
      const float S = sred[tid] + sred[256 + tid];
      const float MX = fmaxf(mred[tid], mred[256 + tid]);
      ((float*)C)[(size_t)by * 4096 + n0 + tid] = S;     // partial sums
      ((float*)AUX)[(size_t)by * 4096 + n0 + tid] = MX;  // partial maxes
    }
    return;
  }

  float awv[4], attp[8][4];
  if constexpr (EPI == 5) {
#pragma unroll
    for (int n = 0; n < 4; ++n) awv[n] = lnb[n0 + wnc + n * 16 + cc];  // att_w
#pragma unroll
    for (int m = 0; m < 8; ++m)
#pragma unroll
      for (int u = 0; u < 4; ++u) attp[m][u] = 0.f;
  }

  bf16_t* myT = smem + wave * 8192;  // EPI4: 64 cols x 128 rows, XOR-swizzled
#pragma unroll
  for (int m = 0; m < 8; ++m) {
#pragma unroll
    for (int n = 0; n < 4; ++n) {
#pragma unroll
      for (int u = 0; u < 4; ++u) {
        const int gr = m0 + wmr + m * 16 + rr + u;
        const int gc = n0 + wnc + n * 16 + cc;
        float v = acc[m][n][u];
        const size_t idx = (size_t)gr * 4096 + gc;
        if constexpr (EPI == 6) {
          // write to M0 (gc<4096) or M1 (gc>=4096), each 4096-stride
          bf16_t* Co = Cb + ((size_t)(gc >> 12) << 24);
          Co[(size_t)gr * 4096 + (gc & 4095)] = __float2bfloat16(v);
        } else if constexpr (EPI == 5) {
          v = __bfloat162float(X0[idx]) + fmaxf(v, 0.f) * rowm[gr];
          Cb[idx] = __float2bfloat16(v);
          attp[m][u] += v * awv[n];
        } else {  // EPI 4: relu*mask, write C and stage C^T in LDS
          v = fmaxf(v, 0.f) * rowm[gr];
          const bf16_t bv = __float2bfloat16(v);
          Cb[idx] = bv;
          const int lrow = m * 16 + rr + u;  // 0..127
          const int lcol = n * 16 + cc;      // 0..63
          myT[lcol * 128 + (lrow ^ ((lcol & 15) << 3))] = bv;
        }
      }
    }
  }
  if constexpr (EPI == 4) {
    bf16_t* CT = (bf16_t*)AUX;
#pragma unroll
    for (int i = 0; i < 16; ++i) {
      const int chunkid = i * 64 + lane;  // 0..1023
      const int lcol = chunkid >> 4;      // 0..63
      const int a8 = chunkid & 15;        // token chunk
      const int lbase = lcol * 128 + ((a8 * 8) ^ ((lcol & 15) << 3));
      short8 vv = *(const short8*)(myT + lbase);
      *(short8*)(CT + (size_t)(n0 + wnc + lcol) * 4096 + (m0 + wmr) + a8 * 8) =
          vv;
    }
  }
  if constexpr (EPI == 5) {
    // att GEMV partials: reduce over 16 cc lanes, then over 4 wc waves
    float* ared = (float*)smem;  // [4 wc][256 rows]
#pragma unroll
    for (int m = 0; m < 8; ++m) {
#pragma unroll
      for (int u = 0; u < 4; ++u) {
        float p = attp[m][u];
        p += __shfl_xor(p, 1);
        p += __shfl_xor(p, 2);
        p += __shfl_xor(p, 4);
        p += __shfl_xor(p, 8);
        if (cc == 0)
          ared[wc * 256 + wr * 128 + m * 16 + (lane >> 4) * 4 + u] = p;
      }
    }
    __syncthreads();
    if (tid < 256) {
      const float s =
          ared[tid] + ared[256 + tid] + ared[512 + tid] + ared[768 + tid];
      ((float*)AUX)[(size_t)bx * 4096 + m0 + tid] = s;  // pAtt[col-panel][row]
    }
  }
}

// ---------------------------------------------------------------- smalls ----
__global__ void att_finish(const float* __restrict__ pAtt,
                           const float* __restrict__ ab,
                           float* __restrict__ satt) {
  const int r = blockIdx.x * 256 + threadIdx.x;
  float s = 0.f;
#pragma unroll
  for (int p = 0; p < 16; ++p) s += pAtt[(size_t)p * 4096 + r];
  satt[r] = 1.f / (1.f + expf(-(s + ab[0])));
}

__global__ void final_kernel(const float* __restrict__ pS,
                             const float* __restrict__ pM,
                             const float* __restrict__ pw,
                             const float* __restrict__ pb,
                             float* __restrict__ out) {
  const int b = blockIdx.x, tid = threadIdx.x;
  float a[20];
#pragma unroll
  for (int k = 0; k < 20; ++k) a[k] = 0.f;
  for (int c = tid; c < 4096; c += 256) {
    const size_t i0 = (size_t)(2 * b) * 4096 + c;
    const size_t i1 = (size_t)(2 * b + 1) * 4096 + c;
    const float s = pS[i0] + pS[i1];
    const float mx = fmaxf(pM[i0], pM[i1]);
    const float v = s * mx;
#pragma unroll
    for (int k = 0; k < 20; ++k) a[k] += v * pw[c * 20 + k];
  }
  __shared__ float red[256][20];
#pragma unroll
  for (int k = 0; k < 20; ++k) red[tid][k] = a[k];
  __syncthreads();
  for (int st = 128; st > 0; st >>= 1) {
    if (tid < st)
      for (int k = 0; k < 20; ++k) red[tid][k] += red[tid + st][k];
    __syncthreads();
  }
  if (tid < 20) out[b * 20 + tid] = red[0][tid] + pb[tid];
}

// ---------------------------------------------------------------- launch ----
extern "C" void kernel_launch(void* const* d_in, const int* in_sizes, int n_in,
                              void* d_out, int out_size, void* d_ws,
                              size_t ws_size, hipStream_t stream) {
  const float* inputs = (const float*)d_in[0];
  const float* adj    = (const float*)d_in[1];
  const float* mask   = (const float*)d_in[2];
  const float* W0     = (const float*)d_in[3];
  const float* W1     = (const float*)d_in[4];
  const float* att_w  = (const float*)d_in[5];
  const float* att_b  = (const float*)d_in[6];
  const float* ln_w   = (const float*)d_in[7];
  const float* ln_b   = (const float*)d_in[8];
  const float* pred_w = (const float*)d_in[9];
  const float* pred_b = (const float*)d_in[10];
  float* out = (float*)d_out;

  const size_t MB32 = (size_t)32 * 1024 * 1024;
  char* ws = (char*)d_ws;
  bf16_t* S0 = (bf16_t*)(ws);             // X^T -> x
  bf16_t* S1 = (bf16_t*)(ws + MB32);      // W0b -> x0
  bf16_t* S2 = (bf16_t*)(ws + 2 * MB32);  // W1b (stacked after S1) -> x0^T
  bf16_t* S3 = (bf16_t*)(ws + 3 * MB32);  // adjb -> (partials after dead)
  bf16_t* S4 = (bf16_t*)(ws + 4 * MB32);  // M0 -> x
  bf16_t* S5 = (bf16_t*)(ws + 5 * MB32);  // M1 (stacked after S4)
  bf16_t* S6 = (bf16_t*)(ws + 6 * MB32);  // ln_w^T
  // partials live in S3's space once adjb is dead (after merged GEMM):
  float* pAtt = (float*)(ws + 3 * MB32);                 // [16][4096]
  float* pS   = (float*)(ws + 3 * MB32 + 512 * 1024);    // [16][4096]
  float* pM   = (float*)(ws + 3 * MB32 + 768 * 1024);    // [16][4096]
  float* satt = (float*)(ws + 3 * MB32 + 1024 * 1024);   // [4096]

  const int SMEM = 131072;  // ring-4 x 2 operands x 16KB
  (void)hipFuncSetAttribute((const void*)gemm_nt<3>,
                            hipFuncAttributeMaxDynamicSharedMemorySize, SMEM);
  (void)hipFuncSetAttribute((const void*)gemm_nt<4>,
                            hipFuncAttributeMaxDynamicSharedMemorySize, SMEM);
  (void)hipFuncSetAttribute((const void*)gemm_nt<5>,
                            hipFuncAttributeMaxDynamicSharedMemorySize, SMEM);
  (void)hipFuncSetAttribute((const void*)gemm_nt<6>,
                            hipFuncAttributeMaxDynamicSharedMemorySize, SMEM);

  // prep: adjb/W0b/W1b converts (one launch), X^T + ln_w^T (one launch)
  convert3_f32_to_bf16<<<dim3(16384, 3), 256, 0, stream>>>(adj, W0, W1, S3,
                                                           S1, S2);
  transpose2_f32_bf16<<<dim3(64, 64, 2), 256, 0, stream>>>(inputs, ln_w, S0,
                                                           S6);
  // merged M0|M1 = NT(adjb, [W0b;W1b]) -> S4|S5 (split writes), 512 blocks
  gemm_nt<6><<<512, 512, SMEM, stream>>>(S3, S1, S4, nullptr, nullptr,
                                         nullptr, nullptr, nullptr);
  // x0 = relu(NT(M0, X^T)) * mask -> S1;  x0^T -> S2 (fused transpose)
  gemm_nt<4><<<256, 512, SMEM, stream>>>(S4, S0, S1, S2, nullptr, mask,
                                         nullptr, nullptr);
  // x = x0 + relu(NT(M1, x0^T)) * mask -> S4; fused att partials -> pAtt
  gemm_nt<5><<<256, 512, SMEM, stream>>>(S5, S2, S4, pAtt, S1, mask, nullptr,
                                         att_w);
  // satt = sigmoid(sum pAtt + ab)
  att_finish<<<16, 256, 0, stream>>>(pAtt, att_b, satt);
  // M5 fused with pool partials: per-block column sum/max of gated h
  gemm_nt<3><<<256, 512, SMEM, stream>>>(S4, S6, pS, pM, nullptr, mask, satt,
                                         ln_b);
  // out[b] = ((sum0+sum1)*(max(max0,max1))) @ pred_w + pred_b
  final_kernel<<<8, 256, 0, stream>>>(pS, pM, pred_w, pred_b, out);
}

// Round 12
// 668.141 us; speedup vs baseline: 1.0432x; 1.0432x over previous
//
#include <hip/hip_runtime.h>
#include <hip/hip_bf16.h>
#include <math.h>

typedef __attribute__((ext_vector_type(8))) short short8;
typedef __attribute__((ext_vector_type(4))) float floatx4;
using bf16_t = __hip_bfloat16;

#define GLOAD16(gp, lp)                                                        \
  __builtin_amdgcn_global_load_lds(                                            \
      (const __attribute__((address_space(1))) unsigned int*)(gp),             \
      (__attribute__((address_space(3))) unsigned int*)(lp), 16, 0, 0)

#define CFENCE() asm volatile("" ::: "memory")
#define BAR()                                                                  \
  do {                                                                         \
    CFENCE();                                                                  \
    __builtin_amdgcn_s_barrier();                                              \
    CFENCE();                                                                  \
  } while (0)

// ---------------------------------------------------------------- converts --
__global__ void convert_f32_to_bf16(const float* __restrict__ in,
                                    bf16_t* __restrict__ out) {
  int i = blockIdx.x * 256 + threadIdx.x;  // 4 elements per thread
  float4 v = ((const float4*)in)[i];
  union { ushort4 u; bf16_t b[4]; } pk;
  pk.b[0] = __float2bfloat16(v.x);
  pk.b[1] = __float2bfloat16(v.y);
  pk.b[2] = __float2bfloat16(v.z);
  pk.b[3] = __float2bfloat16(v.w);
  ((ushort4*)out)[i] = pk.u;
}

// out[c][r] = bf16(in[r][c]); z selects one of 3 independent jobs.
__global__ void transpose3_f32_bf16(const float* __restrict__ s0,
                                    const float* __restrict__ s1,
                                    const float* __restrict__ s2,
                                    bf16_t* __restrict__ d0,
                                    bf16_t* __restrict__ d1,
                                    bf16_t* __restrict__ d2) {
  const float* in = blockIdx.z == 0 ? s0 : (blockIdx.z == 1 ? s1 : s2);
  bf16_t* out = blockIdx.z == 0 ? d0 : (blockIdx.z == 1 ? d1 : d2);
  __shared__ float t[64][65];
  const int r0 = blockIdx.y * 64, c0 = blockIdx.x * 64;
  const int tid = threadIdx.x;
  const int c4 = tid & 15, rr = tid >> 4;
#pragma unroll
  for (int i = 0; i < 4; ++i) {
    const int r = rr + i * 16;
    float4 v = *(const float4*)(in + (size_t)(r0 + r) * 4096 + c0 + c4 * 4);
    t[c4 * 4 + 0][r] = v.x;
    t[c4 * 4 + 1][r] = v.y;
    t[c4 * 4 + 2][r] = v.z;
    t[c4 * 4 + 3][r] = v.w;
  }
  __syncthreads();
  const int r4 = tid & 15, cc = tid >> 4;
#pragma unroll
  for (int i = 0; i < 4; ++i) {
    const int c = cc + i * 16;
    union { ushort4 u; bf16_t b[4]; } pk;
#pragma unroll
    for (int j = 0; j < 4; ++j) pk.b[j] = __float2bfloat16(t[c][r4 * 4 + j]);
    *(ushort4*)(out + (size_t)(c0 + c) * 4096 + r0 + r4 * 4) = pk.u;
  }
}

// single-matrix transpose (ln_w, after M4 when SLOT1 frees)
__global__ void transpose_f32_bf16(const float* __restrict__ in,
                                   bf16_t* __restrict__ out) {
  __shared__ float t[64][65];
  const int r0 = blockIdx.y * 64, c0 = blockIdx.x * 64;
  const int tid = threadIdx.x;
  const int c4 = tid & 15, rr = tid >> 4;
#pragma unroll
  for (int i = 0; i < 4; ++i) {
    const int r = rr + i * 16;
    float4 v = *(const float4*)(in + (size_t)(r0 + r) * 4096 + c0 + c4 * 4);
    t[c4 * 4 + 0][r] = v.x;
    t[c4 * 4 + 1][r] = v.y;
    t[c4 * 4 + 2][r] = v.z;
    t[c4 * 4 + 3][r] = v.w;
  }
  __syncthreads();
  const int r4 = tid & 15, cc = tid >> 4;
#pragma unroll
  for (int i = 0; i < 4; ++i) {
    const int c = cc + i * 16;
    union { ushort4 u; bf16_t b[4]; } pk;
#pragma unroll
    for (int j = 0; j < 4; ++j) pk.b[j] = __float2bfloat16(t[c][r4 * 4 + j]);
    *(ushort4*)(out + (size_t)(c0 + c) * 4096 + r0 + r4 * 4) = pk.u;
  }
}

// ---------------------------------------------------------------- NT GEMM ---
// C[m][n] = sum_k A[m][k]*B[n][k]; 4096^3, bf16 K-fastest operands.
// 256x256 tile, 8 waves (2Mx4N, wave tile 128x64), 16x16x32 MFMA.
// LDS ring-4 of K=32 planes/operand (128 KiB); register-prefetched fragment
// double buffer; per region: {12 ds_read (r+1 frags); 4 gload_lds (plane
// r+3); setprio(1); 32 MFMA (current frags, no waits); setprio(0);
// vmcnt(4); s_barrier}. Pair-XOR swizzle. XCD swizzle (bid&7)*32+bid>>3.
// EPI 0: C=bf16(acc)
// EPI 3: fused M5+pool: per-(by,col) partial sum/max of
//        satt[r]*relu(acc+lnb[c])*mask[r]
// EPI 4: C=bf16(relu(acc)*mask[m]) AND AUX = C^T (LDS-staged transpose)
// EPI 5: C=bf16(X0+relu(acc)*mask[m]) AND AUX=pAtt col-panel partials of
//        x @ att_w (att GEMV fused; lnb param carries att_w)

#define REGION(R, SRD, SWR, FAN, FBN, FAC, FBC)                                \
  {                                                                            \
    _Pragma("unroll") for (int n = 0; n < 4; ++n)                              \
        FBN[n] = *(const short8*)(smem + 32768 + (SRD) * 8192 + offB_e +       \
                                  n * 512);                                    \
    _Pragma("unroll") for (int m = 0; m < 8; ++m)                              \
        FAN[m] = *(const short8*)(smem + (SRD) * 8192 + offA_e + m * 512);     \
    const size_t koW = (size_t)((((R) + 3) & 127) * 32);                       \
    bf16_t* dA = smem + (SWR) * 8192 + wave * 512;                             \
    bf16_t* dB = smem + 32768 + (SWR) * 8192 + wave * 512;                     \
    GLOAD16(A + gAc0 + koW, dA);                                               \
    GLOAD16(A + gAc1 + koW, dA + 4096);                                        \
    GLOAD16(B + gBc0 + koW, dB);                                               \
    GLOAD16(B + gBc1 + koW, dB + 4096);                                        \
    __builtin_amdgcn_s_setprio(1);                                             \
    _Pragma("unroll") for (int m = 0; m < 8; ++m)                              \
        _Pragma("unroll") for (int n = 0; n < 4; ++n)                          \
            acc[m][n] = __builtin_amdgcn_mfma_f32_16x16x32_bf16(               \
                FAC[m], FBC[n], acc[m][n], 0, 0, 0);                           \
    __builtin_amdgcn_s_setprio(0);                                             \
    asm volatile("s_waitcnt vmcnt(4)" ::: "memory");                           \
    BAR();                                                                     \
  }

template <int EPI>
__global__ __launch_bounds__(512, 2) void gemm_nt(
    const bf16_t* __restrict__ A, const bf16_t* __restrict__ B,
    void* __restrict__ C, void* __restrict__ AUX,
    const bf16_t* __restrict__ X0, const float* __restrict__ rowm,
    const float* __restrict__ satt, const float* __restrict__ lnb) {
  extern __shared__ bf16_t smem[];  // 8 planes x 8192 elems = 128 KiB
  const int tid = threadIdx.x;
  const int wave = tid >> 6, lane = tid & 63;
  const int bid = blockIdx.x;
  const int swz = ((bid & 7) << 5) | (bid >> 3);  // XCD-aware remap
  const int by = swz >> 4, bx = swz & 15;
  const int m0 = by * 256, n0 = bx * 256;
  const int wr = wave >> 2, wc = wave & 3;  // 2M x 4N wave grid

  floatx4 acc[8][4] = {};

  // ---- staging source addressing (pre-swizzled global; linear LDS dest).
  const int pr = tid >> 3, ph = tid & 7;
  const int sl8 = ph ^ (pr & 7);                 // logical slot8
  const int rl = (pr << 1) + (sl8 >> 2);         // local row in 128-row call
  const int colg = (sl8 & 3) << 3;               // k element offset (0..24)
  const size_t gAc0 = (size_t)(m0 + rl) * 4096 + colg;
  const size_t gAc1 = gAc0 + (size_t)128 * 4096;
  const size_t gBc0 = (size_t)(n0 + rl) * 4096 + colg;
  const size_t gBc1 = gBc0 + (size_t)128 * 4096;

  // ---- ds_read addressing (16x16x32 frags):
  const int l15 = lane & 15;
  const int phRd = (((lane & 1) << 2) + (lane >> 4)) ^ (l15 >> 1);
  const int offA_e = (wr * 64 + (l15 >> 1)) * 64 + phRd * 8;  // + m*512
  const int offB_e = (wc * 32 + (l15 >> 1)) * 64 + phRd * 8;  // + n*512

  // ---- prologue: stage planes 0,1,2 into slots 0,1,2 (12 loads)
#pragma unroll
  for (int p = 0; p < 3; ++p) {
    bf16_t* dA = smem + p * 8192 + wave * 512;
    bf16_t* dB = smem + 32768 + p * 8192 + wave * 512;
    const size_t ko = (size_t)p * 32;
    GLOAD16(A + gAc0 + ko, dA);
    GLOAD16(A + gAc1 + ko, dA + 4096);
    GLOAD16(B + gBc0 + ko, dB);
    GLOAD16(B + gBc1 + ko, dB + 4096);
  }
  asm volatile("s_waitcnt vmcnt(4)" ::: "memory");  // planes 0,1 landed
  BAR();

  // initial fragment read: region 0 from slot 0
  short8 fA0[8], fB0[4], fA1[8], fB1[4];
#pragma unroll
  for (int n = 0; n < 4; ++n)
    fB0[n] = *(const short8*)(smem + 32768 + offB_e + n * 512);
#pragma unroll
  for (int m = 0; m < 8; ++m)
    fA0[m] = *(const short8*)(smem + offA_e + m * 512);

  for (int r = 0; r < 128; r += 4) {
    REGION(r, 1, 3, fA1, fB1, fA0, fB0)
    REGION(r + 1, 2, 0, fA0, fB0, fA1, fB1)
    REGION(r + 2, 3, 1, fA1, fB1, fA0, fB0)
    REGION(r + 3, 0, 2, fA0, fB0, fA1, fB1)
  }
  asm volatile("s_waitcnt vmcnt(0)" ::: "memory");
  BAR();  // LDS now safe to reuse

  // epilogue: D lane mapping col = lane&15, row = (lane>>4)*4 + u
  const int wmr = wr * 128, wnc = wc * 64;
  const int rr = (lane >> 4) * 4, cc = lane & 15;
  bf16_t* Cb = (bf16_t*)C;

  if constexpr (EPI == 3) {
    // fused: v = satt[r]*relu(acc+lnb[c])*mask[r]; column partial sum & max
    float lb[4];
#pragma unroll
    for (int n = 0; n < 4; ++n) lb[n] = lnb[n0 + wnc + n * 16 + cc];
    float s[4] = {0.f, 0.f, 0.f, 0.f}, mx[4] = {0.f, 0.f, 0.f, 0.f};
#pragma unroll
    for (int m = 0; m < 8; ++m) {
#pragma unroll
      for (int u = 0; u < 4; ++u) {
        const int gr = m0 + wmr + m * 16 + rr + u;
        const float f = satt[gr] * rowm[gr];
#pragma unroll
        for (int n = 0; n < 4; ++n) {
          const float v = fmaxf(acc[m][n][u] + lb[n], 0.f) * f;
          s[n] += v;
          mx[n] = fmaxf(mx[n], v);
        }
      }
    }
#pragma unroll
    for (int n = 0; n < 4; ++n) {
      s[n] += __shfl_xor(s[n], 16);
      s[n] += __shfl_xor(s[n], 32);
      mx[n] = fmaxf(mx[n], __shfl_xor(mx[n], 16));
      mx[n] = fmaxf(mx[n], __shfl_xor(mx[n], 32));
    }
    float* sred = (float*)smem;  // [2][256]
    float* mred = sred + 512;    // [2][256]
    if ((lane >> 4) == 0) {
#pragma unroll
      for (int n = 0; n < 4; ++n) {
        sred[wr * 256 + wnc + n * 16 + cc] = s[n];
        mred[wr * 256 + wnc + n * 16 + cc] = mx[n];
      }
    }
    __syncthreads();
    if (tid < 256) {
      const float S = sred[tid] + sred[256 + tid];
      const float MX = fmaxf(mred[tid], mred[256 + tid]);
      ((float*)C)[(size_t)by * 4096 + n0 + tid] = S;     // partial sums
      ((float*)AUX)[(size_t)by * 4096 + n0 + tid] = MX;  // partial maxes
    }
    return;
  }

  float awv[4], attp[8][4];
  if constexpr (EPI == 5) {
#pragma unroll
    for (int n = 0; n < 4; ++n) awv[n] = lnb[n0 + wnc + n * 16 + cc];  // att_w
#pragma unroll
    for (int m = 0; m < 8; ++m)
#pragma unroll
      for (int u = 0; u < 4; ++u) attp[m][u] = 0.f;
  }

  bf16_t* myT = smem + wave * 8192;  // EPI4: 64 cols x 128 rows, XOR-swizzled
#pragma unroll
  for (int m = 0; m < 8; ++m) {
#pragma unroll
    for (int n = 0; n < 4; ++n) {
#pragma unroll
      for (int u = 0; u < 4; ++u) {
        const int gr = m0 + wmr + m * 16 + rr + u;
        const int gc = n0 + wnc + n * 16 + cc;
        float v = acc[m][n][u];
        const size_t idx = (size_t)gr * 4096 + gc;
        if constexpr (EPI == 0) {
          Cb[idx] = __float2bfloat16(v);
        } else if constexpr (EPI == 5) {
          v = __bfloat162float(X0[idx]) + fmaxf(v, 0.f) * rowm[gr];
          Cb[idx] = __float2bfloat16(v);
          attp[m][u] += v * awv[n];
        } else {  // EPI 4: relu*mask, write C and stage C^T in LDS
          v = fmaxf(v, 0.f) * rowm[gr];
          const bf16_t bv = __float2bfloat16(v);
          Cb[idx] = bv;
          const int lrow = m * 16 + rr + u;  // 0..127
          const int lcol = n * 16 + cc;      // 0..63
          myT[lcol * 128 + (lrow ^ ((lcol & 15) << 3))] = bv;
        }
      }
    }
  }
  if constexpr (EPI == 4) {
    bf16_t* CT = (bf16_t*)AUX;
#pragma unroll
    for (int i = 0; i < 16; ++i) {
      const int chunkid = i * 64 + lane;  // 0..1023
      const int lcol = chunkid >> 4;      // 0..63
      const int a8 = chunkid & 15;        // token chunk
      const int lbase = lcol * 128 + ((a8 * 8) ^ ((lcol & 15) << 3));
      short8 vv = *(const short8*)(myT + lbase);
      *(short8*)(CT + (size_t)(n0 + wnc + lcol) * 4096 + (m0 + wmr) + a8 * 8) =
          vv;
    }
  }
  if constexpr (EPI == 5) {
    // att GEMV partials: reduce over 16 cc lanes, then over 4 wc waves
    float* ared = (float*)smem;  // [4 wc][256 rows]
#pragma unroll
    for (int m = 0; m < 8; ++m) {
#pragma unroll
      for (int u = 0; u < 4; ++u) {
        float p = attp[m][u];
        p += __shfl_xor(p, 1);
        p += __shfl_xor(p, 2);
        p += __shfl_xor(p, 4);
        p += __shfl_xor(p, 8);
        if (cc == 0)
          ared[wc * 256 + wr * 128 + m * 16 + (lane >> 4) * 4 + u] = p;
      }
    }
    __syncthreads();
    if (tid < 256) {
      const float s =
          ared[tid] + ared[256 + tid] + ared[512 + tid] + ared[768 + tid];
      ((float*)AUX)[(size_t)bx * 4096 + m0 + tid] = s;  // pAtt[col-panel][row]
    }
  }
}

// ---------------------------------------------------------------- smalls ----
__global__ void att_finish(const float* __restrict__ pAtt,
                           const float* __restrict__ ab,
                           float* __restrict__ satt) {
  const int r = blockIdx.x * 256 + threadIdx.x;
  float s = 0.f;
#pragma unroll
  for (int p = 0; p < 16; ++p) s += pAtt[(size_t)p * 4096 + r];
  satt[r] = 1.f / (1.f + expf(-(s + ab[0])));
}

__global__ void final_kernel(const float* __restrict__ pS,
                             const float* __restrict__ pM,
                             const float* __restrict__ pw,
                             const float* __restrict__ pb,
                             float* __restrict__ out) {
  const int b = blockIdx.x, tid = threadIdx.x;
  float a[20];
#pragma unroll
  for (int k = 0; k < 20; ++k) a[k] = 0.f;
  for (int c = tid; c < 4096; c += 256) {
    const size_t i0 = (size_t)(2 * b) * 4096 + c;
    const size_t i1 = (size_t)(2 * b + 1) * 4096 + c;
    const float s = pS[i0] + pS[i1];
    const float mx = fmaxf(pM[i0], pM[i1]);
    const float v = s * mx;
#pragma unroll
    for (int k = 0; k < 20; ++k) a[k] += v * pw[c * 20 + k];
  }
  __shared__ float red[256][20];
#pragma unroll
  for (int k = 0; k < 20; ++k) red[tid][k] = a[k];
  __syncthreads();
  for (int st = 128; st > 0; st >>= 1) {
    if (tid < st)
      for (int k = 0; k < 20; ++k) red[tid][k] += red[tid + st][k];
    __syncthreads();
  }
  if (tid < 20) out[b * 20 + tid] = red[0][tid] + pb[tid];
}

// ---------------------------------------------------------------- launch ----
extern "C" void kernel_launch(void* const* d_in, const int* in_sizes, int n_in,
                              void* d_out, int out_size, void* d_ws,
                              size_t ws_size, hipStream_t stream) {
  const float* inputs = (const float*)d_in[0];
  const float* adj    = (const float*)d_in[1];
  const float* mask   = (const float*)d_in[2];
  const float* W0     = (const float*)d_in[3];
  const float* W1     = (const float*)d_in[4];
  const float* att_w  = (const float*)d_in[5];
  const float* att_b  = (const float*)d_in[6];
  const float* ln_w   = (const float*)d_in[7];
  const float* ln_b   = (const float*)d_in[8];
  const float* pred_w = (const float*)d_in[9];
  const float* pred_b = (const float*)d_in[10];
  float* out = (float*)d_out;

  const size_t MB32 = (size_t)32 * 1024 * 1024;
  char* ws = (char*)d_ws;
  bf16_t* SLOT0 = (bf16_t*)(ws);             // XT -> x0T -> x
  bf16_t* SLOT1 = (bf16_t*)(ws + MB32);      // W0T -> ln_wT
  bf16_t* SLOT2 = (bf16_t*)(ws + 2 * MB32);  // adjb
  bf16_t* SLOT3 = (bf16_t*)(ws + 3 * MB32);  // S0T -> S1T
  bf16_t* SLOT4 = (bf16_t*)(ws + 4 * MB32);  // x0
  bf16_t* SLOT5 = (bf16_t*)(ws + 5 * MB32);  // W1T
  float*  pS    = (float*)(ws + 6 * MB32);               // [16][4096]
  float*  pM    = (float*)(ws + 6 * MB32 + 256 * 1024);  // [16][4096]
  float*  pAtt  = (float*)(ws + 6 * MB32 + 512 * 1024);  // [16][4096]
  float*  satt  = (float*)(ws + 6 * MB32 + 768 * 1024);  // [4096]

  const int SMEM = 131072;  // ring-4 x 2 operands x 16KB
  (void)hipFuncSetAttribute((const void*)gemm_nt<0>,
                            hipFuncAttributeMaxDynamicSharedMemorySize, SMEM);
  (void)hipFuncSetAttribute((const void*)gemm_nt<3>,
                            hipFuncAttributeMaxDynamicSharedMemorySize, SMEM);
  (void)hipFuncSetAttribute((const void*)gemm_nt<4>,
                            hipFuncAttributeMaxDynamicSharedMemorySize, SMEM);
  (void)hipFuncSetAttribute((const void*)gemm_nt<5>,
                            hipFuncAttributeMaxDynamicSharedMemorySize, SMEM);

  // upfront prep: XT, W0T, W1T in one launch; adj convert
  transpose3_f32_bf16<<<dim3(64, 64, 3), 256, 0, stream>>>(
      inputs, W0, W1, SLOT0, SLOT1, SLOT5);
  convert_f32_to_bf16<<<16384, 256, 0, stream>>>(adj, SLOT2);
  // M1: S0T = XT (.) W0T
  gemm_nt<0><<<256, 512, SMEM, stream>>>(SLOT0, SLOT1, SLOT3, nullptr, nullptr,
                                         nullptr, nullptr, nullptr);
  // M2: x0 = relu(adjb (.) S0T) * mask[row]; fused x0T write -> SLOT0
  gemm_nt<4><<<256, 512, SMEM, stream>>>(SLOT2, SLOT3, SLOT4, SLOT0, nullptr,
                                         mask, nullptr, nullptr);
  // M3: S1T = x0T (.) W1T
  gemm_nt<0><<<256, 512, SMEM, stream>>>(SLOT0, SLOT5, SLOT3, nullptr, nullptr,
                                         nullptr, nullptr, nullptr);
  // M4: x = x0 + relu(adjb (.) S1T) * mask[row]; fused att partials -> pAtt
  gemm_nt<5><<<256, 512, SMEM, stream>>>(SLOT2, SLOT3, SLOT0, pAtt, SLOT4,
                                         mask, nullptr, att_w);
  // satt = sigmoid(sum pAtt + ab)
  att_finish<<<16, 256, 0, stream>>>(pAtt, att_b, satt);
  // ln_wT (SLOT1 free after M1)
  transpose_f32_bf16<<<dim3(64, 64), 256, 0, stream>>>(ln_w, SLOT1);
  // M5 fused with pool partials: per-block column sum/max of gated h
  gemm_nt<3><<<256, 512, SMEM, stream>>>(SLOT0, SLOT1, pS, pM, nullptr,
                                         mask, satt, ln_b);
  // out[b] = ((sum0+sum1)*(max(max0,max1))) @ pred_w + pred_b
  final_kernel<<<8, 256, 0, stream>>>(pS, pM, pred_w, pred_b, out);
}